// Round 7
// baseline (1549.434 us; speedup 1.0000x reference)
//
#include <hip/hip_runtime.h>
#include <hip/hip_bf16.h>
#include <stdint.h>

#define NEXP 16
#define KSEL 4
#define HDIM 2048
#define IDIM 1024
#define TTOK 2048
#define MAXTILES 80
#define NT1 16            // gemm1 n-tiles (IDIM/64)
#define NT2 32            // gemm2 n-tiles (HDIM/64)
#define MAXB1 (MAXTILES * NT1)   // 1280
#define MAXB2 (MAXTILES * NT2)   // 2560

typedef __attribute__((ext_vector_type(8))) short bf16x8;
typedef __attribute__((ext_vector_type(4))) float f32x4;

__device__ __forceinline__ uint32_t pack2(float a, float b) {
  __hip_bfloat162 h = __float22bfloat162_rn(float2{a, b});
  uint32_t u;
  __builtin_memcpy(&u, &h, 4);
  return u;
}
__device__ __forceinline__ ushort bf1(float a) {
  __hip_bfloat16 h = __float2bfloat16(a);
  ushort u;
  __builtin_memcpy(&u, &h, 2);
  return u;
}
// 8x fp32 -> bf16x8 fragment (4x v_cvt_pk_bf16_f32)
__device__ __forceinline__ bf16x8 cvt8(const float4& lo, const float4& hi) {
  uint4 t;
  t.x = pack2(lo.x, lo.y); t.y = pack2(lo.z, lo.w);
  t.z = pack2(hi.x, hi.y); t.w = pack2(hi.z, hi.w);
  bf16x8 r;
  __builtin_memcpy(&r, &t, 16);
  return r;
}

// ---------------- router: logits, top-4, softmax, x->bf16 ----------------
__global__ __launch_bounds__(256) void router_kernel(
    const float* __restrict__ x, const float* __restrict__ gw,
    ushort* __restrict__ xb, int* __restrict__ topk_id,
    float* __restrict__ topk_w, int* __restrict__ counts)
{
  const int wid = threadIdx.x >> 6;
  const int lane = threadIdx.x & 63;
  const int t = blockIdx.x * 4 + wid;
  const float4* x4 = (const float4*)(x + (size_t)t * HDIM);
  const float4* gw4 = (const float4*)gw;
  float acc[NEXP];
#pragma unroll
  for (int e = 0; e < NEXP; ++e) acc[e] = 0.f;
#pragma unroll
  for (int i = 0; i < HDIM / 256; ++i) {
    const int idx = i * 64 + lane;
    float4 xv = x4[idx];
    uint2 xp;
    xp.x = pack2(xv.x, xv.y);
    xp.y = pack2(xv.z, xv.w);
    *(uint2*)(xb + (size_t)t * HDIM + idx * 4) = xp;
#pragma unroll
    for (int e = 0; e < NEXP; ++e) {
      float4 wv = gw4[e * (HDIM / 4) + idx];
      acc[e] += xv.x * wv.x + xv.y * wv.y + xv.z * wv.z + xv.w * wv.w;
    }
  }
#pragma unroll
  for (int e = 0; e < NEXP; ++e) {
#pragma unroll
    for (int off = 32; off >= 1; off >>= 1)
      acc[e] += __shfl_xor(acc[e], off);
  }
  if (lane == 0) {
    unsigned taken = 0;
    float vals[KSEL];
    int ids[KSEL];
#pragma unroll
    for (int k = 0; k < KSEL; ++k) {
      float bv = -3.4e38f; int bi = 0;
      for (int e = 0; e < NEXP; ++e)
        if (!((taken >> e) & 1u) && acc[e] > bv) { bv = acc[e]; bi = e; }
      taken |= 1u << bi; vals[k] = bv; ids[k] = bi;
    }
    float m = vals[0], s = 0.f, w[KSEL];
#pragma unroll
    for (int k = 0; k < KSEL; ++k) { w[k] = __expf(vals[k] - m); s += w[k]; }
    float is = 1.f / s;
#pragma unroll
    for (int k = 0; k < KSEL; ++k) {
      topk_id[t * KSEL + k] = ids[k];
      topk_w[t * KSEL + k] = w[k] * is;
      atomicAdd(&counts[ids[k]], 1);
    }
  }
}

// ------ plan: offsets + 1D work lists, (e, nt-major, mt-inner) order ------
__global__ void plan_kernel(const int* __restrict__ counts, int* __restrict__ offsets,
                            int* __restrict__ nW1, int* __restrict__ nW2,
                            int* __restrict__ wl1, int* __restrict__ wl2) {
  __shared__ int tiles[NEXP], pre[NEXP];
  const int tid = threadIdx.x;
  if (tid == 0) {
    int s = 0, p = 0;
    for (int e = 0; e < NEXP; ++e) {
      offsets[e] = s; s += counts[e];
      tiles[e] = (counts[e] + 127) >> 7;
      pre[e] = p; p += tiles[e];
    }
    offsets[NEXP] = s;
    *nW1 = p * NT1;
    *nW2 = p * NT2;
  }
  __syncthreads();
  if (tid < NEXP) {
    const int e = tid, T = tiles[e];
    int idx = pre[e] * NT1;
    for (int nt = 0; nt < NT1; ++nt)
      for (int mt = 0; mt < T; ++mt)
        wl1[idx++] = (e << 12) | (nt << 6) | mt;
  } else if (tid < 2 * NEXP) {
    const int e = tid - NEXP, T = tiles[e];
    int idx = pre[e] * NT2;
    for (int nt = 0; nt < NT2; ++nt)
      for (int mt = 0; mt < T; ++mt)
        wl2[idx++] = (e << 12) | (nt << 6) | mt;
  }
}

// ---------------- scatter: bucket tokens by expert ----------------
__global__ __launch_bounds__(256) void scatter_kernel(
    const int* __restrict__ topk_id, const int* __restrict__ offsets,
    int* __restrict__ cursors, int* __restrict__ rowTok, int* __restrict__ inv)
{
  const int t = blockIdx.x * 256 + threadIdx.x;
  if (t >= TTOK) return;
#pragma unroll
  for (int k = 0; k < KSEL; ++k) {
    const int e = topk_id[t * KSEL + k];
    const int pos = atomicAdd(&cursors[e], 1);
    const int row = offsets[e] + pos;
    rowTok[row] = t;
    inv[t * KSEL + k] = row;
  }
}

// -------- GEMM1: h = silu(x.w1g^T)*(x.w1u^T). BM=128 BN=64 BK=32 ---------
// No LDS, no barriers: fragments load straight global->reg (per-lane 16B/32B
// row windows), fp32 weights cvt'd in-register before MFMA. Two named
// register sets = 2-deep prefetch; waves fully independent.
__global__ __launch_bounds__(256) void gemm1_kernel(
    const ushort* __restrict__ xb, const float* __restrict__ w1g,
    const float* __restrict__ w1u, const int* __restrict__ rowTok,
    const int* __restrict__ counts, const int* __restrict__ offsets,
    const int* __restrict__ nW1, const int* __restrict__ wl1,
    ushort* __restrict__ hbuf)
{
  const int nTot = *nW1;
  const int L = (blockIdx.x & 7) * (MAXB1 / 8) + (blockIdx.x >> 3);
  if (L >= nTot) return;
  const int w = wl1[L];
  const int e = w >> 12, nt = (w >> 6) & 63, mt = w & 63;
  const int n_e = counts[e], rowbase = offsets[e];

  const int tid = threadIdx.x;
  const int lane = tid & 63;
  const int wid = tid >> 6;
  const int wr = (wid >> 1) << 6;   // wave row 0/64
  const int wc = (wid & 1) << 5;    // wave col 0/32
  const int lr = lane & 15;
  const int lk = (lane >> 4) << 3;  // k-slot 0/8/16/24

  // Per-lane fragment base pointers (fixed rows; K advances by immediate).
  const ushort* aP[4];
#pragma unroll
  for (int mi = 0; mi < 4; ++mi) {
    const int mrow = mt * 128 + wr + mi * 16 + lr;
    const int tok = rowTok[rowbase + (mrow < n_e ? mrow : n_e - 1)];
    aP[mi] = xb + (size_t)tok * HDIM + lk;
  }
  const float* gP[2];
  const float* uP[2];
  const size_t wb = (size_t)e * IDIM * HDIM + lk;
#pragma unroll
  for (int ni = 0; ni < 2; ++ni) {
    const size_t brow = (size_t)(nt * 64 + wc + ni * 16 + lr) * HDIM;
    gP[ni] = w1g + wb + brow;
    uP[ni] = w1u + wb + brow;
  }

  f32x4 accG[4][2], accU[4][2];
#pragma unroll
  for (int i = 0; i < 4; ++i)
#pragma unroll
    for (int j = 0; j < 2; ++j) {
      accG[i][j] = (f32x4){0.f, 0.f, 0.f, 0.f};
      accU[i][j] = (f32x4){0.f, 0.f, 0.f, 0.f};
    }

  bf16x8 aA[4], aB[4];
  float4 gA[2][2], uA[2][2], gB[2][2], uB[2][2];

  auto LD = [&](bf16x8 (&A)[4], float4 (&G)[2][2], float4 (&U)[2][2], int kt) {
    const int k0 = kt * 32;
#pragma unroll
    for (int mi = 0; mi < 4; ++mi)
      A[mi] = *(const bf16x8*)(aP[mi] + k0);
#pragma unroll
    for (int ni = 0; ni < 2; ++ni) {
      G[ni][0] = *(const float4*)(gP[ni] + k0);
      G[ni][1] = *(const float4*)(gP[ni] + k0 + 4);
      U[ni][0] = *(const float4*)(uP[ni] + k0);
      U[ni][1] = *(const float4*)(uP[ni] + k0 + 4);
    }
  };
  auto SUBSTEP = [&](bf16x8 (&A)[4], float4 (&G)[2][2], float4 (&U)[2][2],
                     int nextKt) {
    bf16x8 bg0 = cvt8(G[0][0], G[0][1]);
    bf16x8 bg1 = cvt8(G[1][0], G[1][1]);
    bf16x8 bu0 = cvt8(U[0][0], U[0][1]);
    bf16x8 bu1 = cvt8(U[1][0], U[1][1]);
    bf16x8 av[4];
#pragma unroll
    for (int mi = 0; mi < 4; ++mi) av[mi] = A[mi];
    LD(A, G, U, nextKt);   // next tile's loads fly during the MFMAs below
#pragma unroll
    for (int mi = 0; mi < 4; ++mi) {
      accG[mi][0] = __builtin_amdgcn_mfma_f32_16x16x32_bf16(av[mi], bg0, accG[mi][0], 0, 0, 0);
      accG[mi][1] = __builtin_amdgcn_mfma_f32_16x16x32_bf16(av[mi], bg1, accG[mi][1], 0, 0, 0);
      accU[mi][0] = __builtin_amdgcn_mfma_f32_16x16x32_bf16(av[mi], bu0, accU[mi][0], 0, 0, 0);
      accU[mi][1] = __builtin_amdgcn_mfma_f32_16x16x32_bf16(av[mi], bu1, accU[mi][1], 0, 0, 0);
    }
  };

  const int NTK = HDIM / 32;  // 64
  LD(aA, gA, uA, 0);
  LD(aB, gB, uB, 1);
  for (int kt = 0; kt < NTK; kt += 2) {
    SUBSTEP(aA, gA, uA, (kt + 2) & (NTK - 1));  // clamp keeps counts static
    SUBSTEP(aB, gB, uB, (kt + 3) & (NTK - 1));
  }

#pragma unroll
  for (int mi = 0; mi < 4; ++mi) {
#pragma unroll
    for (int ni = 0; ni < 2; ++ni) {
      const int col = nt * 64 + wc + ni * 16 + lr;
#pragma unroll
      for (int r = 0; r < 4; ++r) {
        const int mrow = mt * 128 + wr + mi * 16 + ((lane >> 4) << 2) + r;
        if (mrow < n_e) {
          const float gv = accG[mi][ni][r];
          const float uv = accU[mi][ni][r];
          const float hv = (gv / (1.f + __expf(-gv))) * uv;
          hbuf[(size_t)(rowbase + mrow) * IDIM + col] = bf1(hv);
        }
      }
    }
  }
}

// -------- GEMM2: po = h . w2^T (per expert). BM=128 BN=64 BK=32 -----------
__global__ __launch_bounds__(256) void gemm2_kernel(
    const ushort* __restrict__ hbuf, const float* __restrict__ w2,
    const int* __restrict__ counts, const int* __restrict__ offsets,
    const int* __restrict__ nW2, const int* __restrict__ wl2,
    ushort* __restrict__ po)
{
  const int nTot = *nW2;
  const int L = (blockIdx.x & 7) * (MAXB2 / 8) + (blockIdx.x >> 3);
  if (L >= nTot) return;
  const int w = wl2[L];
  const int e = w >> 12, nt = (w >> 6) & 63, mt = w & 63;
  const int n_e = counts[e], rowbase = offsets[e];

  const int tid = threadIdx.x;
  const int lane = tid & 63;
  const int wid = tid >> 6;
  const int wr = (wid >> 1) << 6;
  const int wc = (wid & 1) << 5;
  const int lr = lane & 15;
  const int lk = (lane >> 4) << 3;

  const ushort* aP[4];
#pragma unroll
  for (int mi = 0; mi < 4; ++mi) {
    const int mrow = mt * 128 + wr + mi * 16 + lr;
    aP[mi] = hbuf + (size_t)(rowbase + (mrow < n_e ? mrow : n_e - 1)) * IDIM + lk;
  }
  const float* bP[2];
#pragma unroll
  for (int ni = 0; ni < 2; ++ni) {
    const int brow = nt * 64 + wc + ni * 16 + lr;
    bP[ni] = w2 + (size_t)e * HDIM * IDIM + (size_t)brow * IDIM + lk;
  }

  f32x4 acc[4][2];
#pragma unroll
  for (int i = 0; i < 4; ++i)
#pragma unroll
    for (int j = 0; j < 2; ++j) acc[i][j] = (f32x4){0.f, 0.f, 0.f, 0.f};

  bf16x8 aA[4], aB[4];
  float4 bA[2][2], bB[2][2];

  auto LD = [&](bf16x8 (&A)[4], float4 (&Bv)[2][2], int kt) {
    const int k0 = kt * 32;
#pragma unroll
    for (int mi = 0; mi < 4; ++mi)
      A[mi] = *(const bf16x8*)(aP[mi] + k0);
#pragma unroll
    for (int ni = 0; ni < 2; ++ni) {
      Bv[ni][0] = *(const float4*)(bP[ni] + k0);
      Bv[ni][1] = *(const float4*)(bP[ni] + k0 + 4);
    }
  };
  auto SUBSTEP = [&](bf16x8 (&A)[4], float4 (&Bv)[2][2], int nextKt) {
    bf16x8 b0 = cvt8(Bv[0][0], Bv[0][1]);
    bf16x8 b1 = cvt8(Bv[1][0], Bv[1][1]);
    bf16x8 av[4];
#pragma unroll
    for (int mi = 0; mi < 4; ++mi) av[mi] = A[mi];
    LD(A, Bv, nextKt);
#pragma unroll
    for (int mi = 0; mi < 4; ++mi) {
      acc[mi][0] = __builtin_amdgcn_mfma_f32_16x16x32_bf16(av[mi], b0, acc[mi][0], 0, 0, 0);
      acc[mi][1] = __builtin_amdgcn_mfma_f32_16x16x32_bf16(av[mi], b1, acc[mi][1], 0, 0, 0);
    }
  };

  const int NTK = IDIM / 32;  // 32
  LD(aA, bA, 0);
  LD(aB, bB, 1);
  for (int kt = 0; kt < NTK; kt += 2) {
    SUBSTEP(aA, bA, (kt + 2) & (NTK - 1));
    SUBSTEP(aB, bB, (kt + 3) & (NTK - 1));
  }

#pragma unroll
  for (int mi = 0; mi < 4; ++mi) {
#pragma unroll
    for (int ni = 0; ni < 2; ++ni) {
      const int col = nt * 64 + wc + ni * 16 + lr;
#pragma unroll
      for (int r = 0; r < 4; ++r) {
        const int mrow = mt * 128 + wr + mi * 16 + ((lane >> 4) << 2) + r;
        if (mrow < n_e)
          po[(size_t)(rowbase + mrow) * HDIM + col] = bf1(acc[mi][ni][r]);
      }
    }
  }
}

// ---------------- combine: out[t] = sum_k w_k * po[row_k] -----------------
__global__ __launch_bounds__(256) void combine_kernel(
    const ushort* __restrict__ po, const int* __restrict__ inv,
    const float* __restrict__ tw, float* __restrict__ out)
{
  const int t = blockIdx.x;
  const int r0 = inv[t * 4 + 0], r1 = inv[t * 4 + 1];
  const int r2 = inv[t * 4 + 2], r3 = inv[t * 4 + 3];
  const float w0 = tw[t * 4 + 0], w1 = tw[t * 4 + 1];
  const float w2v = tw[t * 4 + 2], w3 = tw[t * 4 + 3];
  const int i = threadIdx.x;  // HDIM/8 == 256 lanes, 8 elems each
  uint4 v0 = *(const uint4*)(po + (size_t)r0 * HDIM + i * 8);
  uint4 v1 = *(const uint4*)(po + (size_t)r1 * HDIM + i * 8);
  uint4 v2 = *(const uint4*)(po + (size_t)r2 * HDIM + i * 8);
  uint4 v3 = *(const uint4*)(po + (size_t)r3 * HDIM + i * 8);
  float o[8];
#pragma unroll
  for (int w = 0; w < 4; ++w) {
    const uint32_t a = (&v0.x)[w], b = (&v1.x)[w], c = (&v2.x)[w], d = (&v3.x)[w];
    o[w * 2 + 0] = w0 * __builtin_bit_cast(float, a << 16) +
                   w1 * __builtin_bit_cast(float, b << 16) +
                   w2v * __builtin_bit_cast(float, c << 16) +
                   w3 * __builtin_bit_cast(float, d << 16);
    o[w * 2 + 1] = w0 * __builtin_bit_cast(float, a & 0xffff0000u) +
                   w1 * __builtin_bit_cast(float, b & 0xffff0000u) +
                   w2v * __builtin_bit_cast(float, c & 0xffff0000u) +
                   w3 * __builtin_bit_cast(float, d & 0xffff0000u);
  }
  float4* o4 = (float4*)(out + (size_t)t * HDIM + i * 8);
  o4[0] = (float4){o[0], o[1], o[2], o[3]};
  o4[1] = (float4){o[4], o[5], o[6], o[7]};
}

extern "C" void kernel_launch(void* const* d_in, const int* in_sizes, int n_in,
                              void* d_out, int out_size, void* d_ws, size_t ws_size,
                              hipStream_t stream) {
  const float* x   = (const float*)d_in[0];
  const float* gw  = (const float*)d_in[1];
  const float* w1g = (const float*)d_in[2];
  const float* w1u = (const float*)d_in[3];
  const float* w2  = (const float*)d_in[4];
  float* out = (float*)d_out;

  char* ws = (char*)d_ws;
  ushort* xb     = (ushort*)(ws + 0);
  ushort* hbuf   = (ushort*)(ws + 8388608);
  ushort* po     = (ushort*)(ws + 25165824);
  int*    tkid   = (int*)   (ws + 58720256);
  float*  tkw    = (float*) (ws + 58753024);
  int*    rowTok = (int*)   (ws + 58785792);
  int*    inv    = (int*)   (ws + 58818560);
  int*    ctrl   = (int*)   (ws + 58851328);
  int* counts  = ctrl;          // 16
  int* cursors = ctrl + 16;     // 16
  int* offsets = ctrl + 32;     // 17
  int* nW1     = ctrl + 50;     // 1
  int* nW2     = ctrl + 51;     // 1
  int* wl1     = ctrl + 64;     // MAXB1 (1280)
  int* wl2     = ctrl + 64 + MAXB1;  // MAXB2 (2560)

  (void)hipMemsetAsync(ctrl, 0, 256, stream);
  router_kernel<<<TTOK / 4, 256, 0, stream>>>(x, gw, xb, tkid, tkw, counts);
  plan_kernel<<<1, 64, 0, stream>>>(counts, offsets, nW1, nW2, wl1, wl2);
  scatter_kernel<<<TTOK / 256, 256, 0, stream>>>(tkid, offsets, cursors, rowTok, inv);
  gemm1_kernel<<<MAXB1, 256, 0, stream>>>(xb, w1g, w1u, rowTok, counts, offsets,
                                          nW1, wl1, hbuf);
  gemm2_kernel<<<MAXB2, 256, 0, stream>>>(hbuf, w2, counts, offsets,
                                          nW2, wl2, po);
  combine_kernel<<<TTOK, 256, 0, stream>>>(po, inv, tkw, out);
}

// Round 8
// 496.755 us; speedup vs baseline: 3.1191x; 3.1191x over previous
//
#include <hip/hip_runtime.h>
#include <hip/hip_bf16.h>
#include <stdint.h>

#define NEXP 16
#define KSEL 4
#define HDIM 2048
#define IDIM 1024
#define TTOK 2048
#define MAXTILES 80
#define NTA 8                    // gemmA n-tiles (IDIM/128)
#define NTB 16                   // gemmB n-tiles (HDIM/128)
#define MAXBA (MAXTILES * NTA)   // 640
#define MAXBB (MAXTILES * NTB)   // 1280

typedef __attribute__((ext_vector_type(8))) short bf16x8;
typedef __attribute__((ext_vector_type(4))) float f32x4;
typedef unsigned int u32;

__device__ __forceinline__ uint32_t pack2(float a, float b) {
  __hip_bfloat162 h = __float22bfloat162_rn(float2{a, b});
  uint32_t u;
  __builtin_memcpy(&u, &h, 4);
  return u;
}
__device__ __forceinline__ ushort bf1(float a) {
  __hip_bfloat16 h = __float2bfloat16(a);
  ushort u;
  __builtin_memcpy(&u, &h, 2);
  return u;
}
__device__ __forceinline__ float bf2f(ushort u) {
  uint32_t v = (uint32_t)u << 16;
  float f;
  __builtin_memcpy(&f, &v, 4);
  return f;
}
// async global->LDS, 16B per lane. Dest is wave-uniform base + lane*16
// (linear); gather/swizzle lives in the per-lane SOURCE address (m97/m173).
__device__ __forceinline__ void gload16(const ushort* g, ushort* l) {
  __builtin_amdgcn_global_load_lds(
      (const __attribute__((address_space(1))) u32*)g,
      (__attribute__((address_space(3))) u32*)l, 16, 0, 0);
}
// LDS tile [128 rows][32 bf16] (64B rows, 4 chunks of 16B). Stored chunk =
// linear; source chunk = ck ^ s(row); read chunk = q ^ s(row); s=(row>>1)&3.
// Read banks: 8 distinct 16B slots per 16-lane group -> 2-way (free, m136).
__device__ __forceinline__ int swzread(int row, int q) {
  return row * 32 + ((q ^ ((row >> 1) & 3)) << 3);
}

// ---------------- cvt: fp32 -> bf16 streaming ----------------
__global__ __launch_bounds__(256) void cvtw_kernel(
    const float* __restrict__ src, ushort* __restrict__ dst, int n8)
{
  const int stride = gridDim.x * 256;
  for (int i = blockIdx.x * 256 + threadIdx.x; i < n8; i += stride) {
    float4 a = ((const float4*)src)[i * 2];
    float4 b = ((const float4*)src)[i * 2 + 1];
    uint4 t;
    t.x = pack2(a.x, a.y); t.y = pack2(a.z, a.w);
    t.z = pack2(b.x, b.y); t.w = pack2(b.z, b.w);
    ((uint4*)dst)[i] = t;
  }
}

// ---------------- router: logits, top-4, softmax, x->bf16 ----------------
__global__ __launch_bounds__(256) void router_kernel(
    const float* __restrict__ x, const float* __restrict__ gw,
    ushort* __restrict__ xb, int* __restrict__ topk_id,
    float* __restrict__ topk_w, int* __restrict__ counts)
{
  const int wid = threadIdx.x >> 6;
  const int lane = threadIdx.x & 63;
  const int t = blockIdx.x * 4 + wid;
  const float4* x4 = (const float4*)(x + (size_t)t * HDIM);
  const float4* gw4 = (const float4*)gw;
  float acc[NEXP];
#pragma unroll
  for (int e = 0; e < NEXP; ++e) acc[e] = 0.f;
#pragma unroll
  for (int i = 0; i < HDIM / 256; ++i) {
    const int idx = i * 64 + lane;
    float4 xv = x4[idx];
    uint2 xp;
    xp.x = pack2(xv.x, xv.y);
    xp.y = pack2(xv.z, xv.w);
    *(uint2*)(xb + (size_t)t * HDIM + idx * 4) = xp;
#pragma unroll
    for (int e = 0; e < NEXP; ++e) {
      float4 wv = gw4[e * (HDIM / 4) + idx];
      acc[e] += xv.x * wv.x + xv.y * wv.y + xv.z * wv.z + xv.w * wv.w;
    }
  }
#pragma unroll
  for (int e = 0; e < NEXP; ++e) {
#pragma unroll
    for (int off = 32; off >= 1; off >>= 1)
      acc[e] += __shfl_xor(acc[e], off);
  }
  if (lane == 0) {
    unsigned taken = 0;
    float vals[KSEL];
    int ids[KSEL];
#pragma unroll
    for (int k = 0; k < KSEL; ++k) {
      float bv = -3.4e38f; int bi = 0;
      for (int e = 0; e < NEXP; ++e)
        if (!((taken >> e) & 1u) && acc[e] > bv) { bv = acc[e]; bi = e; }
      taken |= 1u << bi; vals[k] = bv; ids[k] = bi;
    }
    float m = vals[0], s = 0.f, w[KSEL];
#pragma unroll
    for (int k = 0; k < KSEL; ++k) { w[k] = __expf(vals[k] - m); s += w[k]; }
    float is = 1.f / s;
#pragma unroll
    for (int k = 0; k < KSEL; ++k) {
      topk_id[t * KSEL + k] = ids[k];
      topk_w[t * KSEL + k] = w[k] * is;
      atomicAdd(&counts[ids[k]], 1);
    }
  }
}

// ------ plan: offsets + 1D work lists, (e, nt-major, mt-inner) order ------
__global__ void plan_kernel(const int* __restrict__ counts, int* __restrict__ offsets,
                            int* __restrict__ nWA, int* __restrict__ nWB,
                            int* __restrict__ wlA, int* __restrict__ wlB) {
  __shared__ int tiles[NEXP], pre[NEXP];
  const int tid = threadIdx.x;
  if (tid == 0) {
    int s = 0, p = 0;
    for (int e = 0; e < NEXP; ++e) {
      offsets[e] = s; s += counts[e];
      tiles[e] = (counts[e] + 127) >> 7;
      pre[e] = p; p += tiles[e];
    }
    offsets[NEXP] = s;
    *nWA = p * NTA;
    *nWB = p * NTB;
  }
  __syncthreads();
  if (tid < NEXP) {
    const int e = tid, T = tiles[e];
    int idx = pre[e] * NTA;
    for (int nt = 0; nt < NTA; ++nt)
      for (int mt = 0; mt < T; ++mt)
        wlA[idx++] = (e << 12) | (nt << 6) | mt;
  } else if (tid < 2 * NEXP) {
    const int e = tid - NEXP, T = tiles[e];
    int idx = pre[e] * NTB;
    for (int nt = 0; nt < NTB; ++nt)
      for (int mt = 0; mt < T; ++mt)
        wlB[idx++] = (e << 12) | (nt << 6) | mt;
  }
}

// ---------------- scatter: bucket tokens by expert ----------------
__global__ __launch_bounds__(256) void scatter_kernel(
    const int* __restrict__ topk_id, const int* __restrict__ offsets,
    int* __restrict__ cursors, int* __restrict__ rowTok, int* __restrict__ inv)
{
  const int t = blockIdx.x * 256 + threadIdx.x;
  if (t >= TTOK) return;
#pragma unroll
  for (int k = 0; k < KSEL; ++k) {
    const int e = topk_id[t * KSEL + k];
    const int pos = atomicAdd(&cursors[e], 1);
    const int row = offsets[e] + pos;
    rowTok[row] = t;
    inv[t * KSEL + k] = row;
  }
}

// ------- gemmA: out[rows][1024] = gathered_x . W^T  (m97 structure) -------
// 128x128 tile, BK=32, 4 waves x 4x4 frags, global_load_lds staging.
__global__ __launch_bounds__(256) void gemmA_kernel(
    const ushort* __restrict__ xb, const ushort* __restrict__ wb,
    const int* __restrict__ rowTok, const int* __restrict__ counts,
    const int* __restrict__ offsets, const int* __restrict__ nW,
    const int* __restrict__ wl, ushort* __restrict__ outb)
{
  const int nTot = *nW;
  const int L = (blockIdx.x & 7) * (MAXBA / 8) + (blockIdx.x >> 3);
  if (L >= nTot) return;
  const int w = wl[L];
  const int e = w >> 12, nt = (w >> 6) & 63, mt = w & 63;
  const int n_e = counts[e], rowbase = offsets[e];

  __shared__ ushort As[2][128 * 32];
  __shared__ ushort Bs[2][128 * 32];

  const int tid = threadIdx.x;
  const int r0 = tid >> 2;                   // staging row (call0), 0..63
  const int ck = tid & 3;                    // linear 16B chunk
  const int sch = (ck ^ ((r0 >> 1) & 3)) << 3;  // swizzled source elem offset

  const int ar0 = mt * 128 + r0, ar1 = ar0 + 64;
  const int tok0 = rowTok[rowbase + (ar0 < n_e ? ar0 : n_e - 1)];
  const int tok1 = rowTok[rowbase + (ar1 < n_e ? ar1 : n_e - 1)];
  const ushort* pA0 = xb + (size_t)tok0 * HDIM + sch;
  const ushort* pA1 = xb + (size_t)tok1 * HDIM + sch;
  const size_t wbase = (size_t)e * IDIM * HDIM;
  const ushort* pB0 = wb + wbase + (size_t)(nt * 128 + r0) * HDIM + sch;
  const ushort* pB1 = wb + wbase + (size_t)(nt * 128 + r0 + 64) * HDIM + sch;

  const int lane = tid & 63;
  const int wid = tid >> 6;
  const int wr = (wid >> 1) << 6;
  const int wc = (wid & 1) << 6;
  const int lr = lane & 15;
  const int q = lane >> 4;

  f32x4 acc[4][4];
#pragma unroll
  for (int i = 0; i < 4; ++i)
#pragma unroll
    for (int j = 0; j < 4; ++j) acc[i][j] = (f32x4){0.f, 0.f, 0.f, 0.f};

  auto STAGE = [&](int b) {
    gload16(pA0, &As[b][tid * 8]);
    gload16(pA1, &As[b][2048 + tid * 8]);
    gload16(pB0, &Bs[b][tid * 8]);
    gload16(pB1, &Bs[b][2048 + tid * 8]);
    pA0 += 32; pA1 += 32; pB0 += 32; pB1 += 32;
  };

  const int NTK = HDIM / 32;  // 64
  STAGE(0);
  __syncthreads();
  int buf = 0;
  for (int kt = 0; kt < NTK; ++kt) {
    if (kt + 1 < NTK) STAGE(buf ^ 1);
    bf16x8 af[4], bfr[4];
#pragma unroll
    for (int mi = 0; mi < 4; ++mi) {
      const int row = wr + mi * 16 + lr;
      af[mi] = *(const bf16x8*)&As[buf][swzread(row, q)];
    }
#pragma unroll
    for (int ni = 0; ni < 4; ++ni) {
      const int row = wc + ni * 16 + lr;
      bfr[ni] = *(const bf16x8*)&Bs[buf][swzread(row, q)];
    }
#pragma unroll
    for (int mi = 0; mi < 4; ++mi)
#pragma unroll
      for (int ni = 0; ni < 4; ++ni)
        acc[mi][ni] = __builtin_amdgcn_mfma_f32_16x16x32_bf16(af[mi], bfr[ni], acc[mi][ni], 0, 0, 0);
    __syncthreads();
    buf ^= 1;
  }

#pragma unroll
  for (int mi = 0; mi < 4; ++mi) {
#pragma unroll
    for (int ni = 0; ni < 4; ++ni) {
      const int col = nt * 128 + wc + ni * 16 + lr;
#pragma unroll
      for (int r = 0; r < 4; ++r) {
        const int mrow = mt * 128 + wr + mi * 16 + q * 4 + r;
        if (mrow < n_e)
          outb[(size_t)(rowbase + mrow) * IDIM + col] = bf1(acc[mi][ni][r]);
      }
    }
  }
}

// ------- gemmB: po[rows][2048] = hbuf . w2^T  (same structure) -------
__global__ __launch_bounds__(256) void gemmB_kernel(
    const ushort* __restrict__ hb, const ushort* __restrict__ wb,
    const int* __restrict__ counts, const int* __restrict__ offsets,
    const int* __restrict__ nW, const int* __restrict__ wl,
    ushort* __restrict__ po)
{
  const int nTot = *nW;
  const int L = (blockIdx.x & 7) * (MAXBB / 8) + (blockIdx.x >> 3);
  if (L >= nTot) return;
  const int w = wl[L];
  const int e = w >> 12, nt = (w >> 6) & 63, mt = w & 63;
  const int n_e = counts[e], rowbase = offsets[e];

  __shared__ ushort As[2][128 * 32];
  __shared__ ushort Bs[2][128 * 32];

  const int tid = threadIdx.x;
  const int r0 = tid >> 2;
  const int ck = tid & 3;
  const int sch = (ck ^ ((r0 >> 1) & 3)) << 3;

  const int ar0 = mt * 128 + r0, ar1 = ar0 + 64;
  const int g0 = rowbase + (ar0 < n_e ? ar0 : n_e - 1);
  const int g1 = rowbase + (ar1 < n_e ? ar1 : n_e - 1);
  const ushort* pA0 = hb + (size_t)g0 * IDIM + sch;
  const ushort* pA1 = hb + (size_t)g1 * IDIM + sch;
  const size_t wbase = (size_t)e * HDIM * IDIM;
  const ushort* pB0 = wb + wbase + (size_t)(nt * 128 + r0) * IDIM + sch;
  const ushort* pB1 = wb + wbase + (size_t)(nt * 128 + r0 + 64) * IDIM + sch;

  const int lane = tid & 63;
  const int wid = tid >> 6;
  const int wr = (wid >> 1) << 6;
  const int wc = (wid & 1) << 6;
  const int lr = lane & 15;
  const int q = lane >> 4;

  f32x4 acc[4][4];
#pragma unroll
  for (int i = 0; i < 4; ++i)
#pragma unroll
    for (int j = 0; j < 4; ++j) acc[i][j] = (f32x4){0.f, 0.f, 0.f, 0.f};

  auto STAGE = [&](int b) {
    gload16(pA0, &As[b][tid * 8]);
    gload16(pA1, &As[b][2048 + tid * 8]);
    gload16(pB0, &Bs[b][tid * 8]);
    gload16(pB1, &Bs[b][2048 + tid * 8]);
    pA0 += 32; pA1 += 32; pB0 += 32; pB1 += 32;
  };

  const int NTK = IDIM / 32;  // 32
  STAGE(0);
  __syncthreads();
  int buf = 0;
  for (int kt = 0; kt < NTK; ++kt) {
    if (kt + 1 < NTK) STAGE(buf ^ 1);
    bf16x8 af[4], bfr[4];
#pragma unroll
    for (int mi = 0; mi < 4; ++mi) {
      const int row = wr + mi * 16 + lr;
      af[mi] = *(const bf16x8*)&As[buf][swzread(row, q)];
    }
#pragma unroll
    for (int ni = 0; ni < 4; ++ni) {
      const int row = wc + ni * 16 + lr;
      bfr[ni] = *(const bf16x8*)&Bs[buf][swzread(row, q)];
    }
#pragma unroll
    for (int mi = 0; mi < 4; ++mi)
#pragma unroll
      for (int ni = 0; ni < 4; ++ni)
        acc[mi][ni] = __builtin_amdgcn_mfma_f32_16x16x32_bf16(af[mi], bfr[ni], acc[mi][ni], 0, 0, 0);
    __syncthreads();
    buf ^= 1;
  }

#pragma unroll
  for (int mi = 0; mi < 4; ++mi) {
#pragma unroll
    for (int ni = 0; ni < 4; ++ni) {
      const int col = nt * 128 + wc + ni * 16 + lr;
#pragma unroll
      for (int r = 0; r < 4; ++r) {
        const int mrow = mt * 128 + wr + mi * 16 + q * 4 + r;
        if (mrow < n_e)
          po[(size_t)(rowbase + mrow) * HDIM + col] = bf1(acc[mi][ni][r]);
      }
    }
  }
}

// ---------------- silu: h = silu(g) * u, elementwise bf16 ----------------
__global__ __launch_bounds__(256) void silu_kernel(
    const ushort* __restrict__ g, const ushort* __restrict__ u,
    ushort* __restrict__ h, int n8)
{
  const int stride = gridDim.x * 256;
  for (int i = blockIdx.x * 256 + threadIdx.x; i < n8; i += stride) {
    uint4 gv = ((const uint4*)g)[i];
    uint4 uv = ((const uint4*)u)[i];
    uint4 hv;
#pragma unroll
    for (int wd = 0; wd < 4; ++wd) {
      const uint32_t gw2 = (&gv.x)[wd], uw2 = (&uv.x)[wd];
      const float g0 = bf2f((ushort)(gw2 & 0xffff));
      const float g1 = bf2f((ushort)(gw2 >> 16));
      const float u0 = bf2f((ushort)(uw2 & 0xffff));
      const float u1 = bf2f((ushort)(uw2 >> 16));
      const float h0 = (g0 / (1.f + __expf(-g0))) * u0;
      const float h1 = (g1 / (1.f + __expf(-g1))) * u1;
      (&hv.x)[wd] = pack2(h0, h1);
    }
    ((uint4*)h)[i] = hv;
  }
}

// ---------------- combine: out[t] = sum_k w_k * po[row_k] -----------------
__global__ __launch_bounds__(256) void combine_kernel(
    const ushort* __restrict__ po, const int* __restrict__ inv,
    const float* __restrict__ tw, float* __restrict__ out)
{
  const int t = blockIdx.x;
  const int r0 = inv[t * 4 + 0], r1 = inv[t * 4 + 1];
  const int r2 = inv[t * 4 + 2], r3 = inv[t * 4 + 3];
  const float w0 = tw[t * 4 + 0], w1 = tw[t * 4 + 1];
  const float w2v = tw[t * 4 + 2], w3 = tw[t * 4 + 3];
  const int i = threadIdx.x;
  uint4 v0 = *(const uint4*)(po + (size_t)r0 * HDIM + i * 8);
  uint4 v1 = *(const uint4*)(po + (size_t)r1 * HDIM + i * 8);
  uint4 v2 = *(const uint4*)(po + (size_t)r2 * HDIM + i * 8);
  uint4 v3 = *(const uint4*)(po + (size_t)r3 * HDIM + i * 8);
  float o[8];
#pragma unroll
  for (int w = 0; w < 4; ++w) {
    const uint32_t a = (&v0.x)[w], b = (&v1.x)[w], c = (&v2.x)[w], d = (&v3.x)[w];
    o[w * 2 + 0] = w0 * __builtin_bit_cast(float, a << 16) +
                   w1 * __builtin_bit_cast(float, b << 16) +
                   w2v * __builtin_bit_cast(float, c << 16) +
                   w3 * __builtin_bit_cast(float, d << 16);
    o[w * 2 + 1] = w0 * __builtin_bit_cast(float, a & 0xffff0000u) +
                   w1 * __builtin_bit_cast(float, b & 0xffff0000u) +
                   w2v * __builtin_bit_cast(float, c & 0xffff0000u) +
                   w3 * __builtin_bit_cast(float, d & 0xffff0000u);
  }
  float4* o4 = (float4*)(out + (size_t)t * HDIM + i * 8);
  o4[0] = (float4){o[0], o[1], o[2], o[3]};
  o4[1] = (float4){o[4], o[5], o[6], o[7]};
}

extern "C" void kernel_launch(void* const* d_in, const int* in_sizes, int n_in,
                              void* d_out, int out_size, void* d_ws, size_t ws_size,
                              hipStream_t stream) {
  const float* x   = (const float*)d_in[0];
  const float* gw  = (const float*)d_in[1];
  const float* w1g = (const float*)d_in[2];
  const float* w1u = (const float*)d_in[3];
  const float* w2  = (const float*)d_in[4];
  float* out = (float*)d_out;

  char* ws = (char*)d_ws;
  // layout (bytes):
  //   xb    [2048][2048] bf16    @ 0          ( 8 MiB)
  //   wbuf  bf16 weights (reused)@ 8388608    (64 MiB)  w1g_b -> w1u_b -> w2_b
  //   gbuf  [8192][1024] bf16    @ 75497472   (16 MiB)
  //   ubuf  [8192][1024] bf16    @ 92274688   (16 MiB)
  //   hbuf  [8192][1024] bf16    @ 109051904  (16 MiB)
  //   po    [8192][2048] bf16    @ 125829120  (32 MiB)
  //   tkid/tkw/rowTok/inv        @ 159383552  (128 KiB)
  //   ctrl + work lists          @ 159514624
  ushort* xb   = (ushort*)(ws + 0);
  ushort* wbuf = (ushort*)(ws + 8388608);
  ushort* gbuf = (ushort*)(ws + 75497472);
  ushort* ubuf = (ushort*)(ws + 92274688);
  ushort* hbuf = (ushort*)(ws + 109051904);
  ushort* po   = (ushort*)(ws + 125829120);
  int*    tkid   = (int*)(ws + 159383552);
  float*  tkw    = (float*)(ws + 159383552 + 32768);
  int*    rowTok = (int*)(ws + 159383552 + 65536);
  int*    inv    = (int*)(ws + 159383552 + 98304);
  int*    ctrl   = (int*)(ws + 159514624);
  int* counts  = ctrl;           // 16
  int* cursors = ctrl + 16;      // 16
  int* offsets = ctrl + 32;      // 17
  int* nWA     = ctrl + 50;      // 1
  int* nWB     = ctrl + 51;      // 1
  int* wlA     = ctrl + 64;      // MAXBA (640)
  int* wlB     = ctrl + 64 + MAXBA;  // MAXBB (1280)

  const int NW8 = (NEXP * IDIM * HDIM) / 8;  // 4194304 (same for w1g/w1u/w2)

  (void)hipMemsetAsync(ctrl, 0, 256, stream);
  router_kernel<<<TTOK / 4, 256, 0, stream>>>(x, gw, xb, tkid, tkw, counts);
  plan_kernel<<<1, 64, 0, stream>>>(counts, offsets, nWA, nWB, wlA, wlB);
  scatter_kernel<<<TTOK / 256, 256, 0, stream>>>(tkid, offsets, cursors, rowTok, inv);

  // gate pass
  cvtw_kernel<<<2048, 256, 0, stream>>>(w1g, wbuf, NW8);
  gemmA_kernel<<<MAXBA, 256, 0, stream>>>(xb, wbuf, rowTok, counts, offsets,
                                          nWA, wlA, gbuf);
  // up pass (wbuf reused; stream order serializes)
  cvtw_kernel<<<2048, 256, 0, stream>>>(w1u, wbuf, NW8);
  gemmA_kernel<<<MAXBA, 256, 0, stream>>>(xb, wbuf, rowTok, counts, offsets,
                                          nWA, wlA, ubuf);
  // h = silu(g) * u
  silu_kernel<<<2048, 256, 0, stream>>>(gbuf, ubuf, hbuf, (TTOK * KSEL * IDIM) / 8);
  // down pass
  cvtw_kernel<<<2048, 256, 0, stream>>>(w2, wbuf, NW8);
  gemmB_kernel<<<MAXBB, 256, 0, stream>>>(hbuf, wbuf, counts, offsets,
                                          nWB, wlB, po);
  combine_kernel<<<TTOK, 256, 0, stream>>>(po, inv, tkw, out);
}

// Round 9
// 379.281 us; speedup vs baseline: 4.0852x; 1.3097x over previous
//
#include <hip/hip_runtime.h>
#include <hip/hip_bf16.h>
#include <stdint.h>

#define NEXP 16
#define KSEL 4
#define HDIM 2048
#define IDIM 1024
#define TTOK 2048
#define MAXTILES 80
#define NTA 8                    // gemmA n-tiles (IDIM/128)
#define NTB 16                   // gemmB n-tiles (HDIM/128)
#define MAXBA (MAXTILES * NTA)   // 640
#define MAXBB (MAXTILES * NTB)   // 1280

typedef __attribute__((ext_vector_type(8))) short bf16x8;
typedef __attribute__((ext_vector_type(4))) float f32x4;
typedef unsigned int u32;

__device__ __forceinline__ uint32_t pack2(float a, float b) {
  __hip_bfloat162 h = __float22bfloat162_rn(float2{a, b});
  uint32_t u;
  __builtin_memcpy(&u, &h, 4);
  return u;
}
__device__ __forceinline__ ushort bf1(float a) {
  __hip_bfloat16 h = __float2bfloat16(a);
  ushort u;
  __builtin_memcpy(&u, &h, 2);
  return u;
}
__device__ __forceinline__ float bf2f(ushort u) {
  uint32_t v = (uint32_t)u << 16;
  float f;
  __builtin_memcpy(&f, &v, 4);
  return f;
}
// async global->LDS, 16B per lane; linear dest, per-lane (gathered/swizzled)
// source address (m97/m173 pattern).
__device__ __forceinline__ void gload16(const ushort* g, ushort* l) {
  __builtin_amdgcn_global_load_lds(
      (const __attribute__((address_space(1))) u32*)g,
      (__attribute__((address_space(3))) u32*)l, 16, 0, 0);
}
// LDS tile [128 rows][32 bf16]; stored linear, source chunk pre-XOR'd,
// read chunk XOR'd with row -> conflict-free (verified 0 conflicts R3-R8).
__device__ __forceinline__ int swzread(int row, int q) {
  return row * 32 + ((q ^ ((row >> 1) & 3)) << 3);
}

// ---------------- cvt: fp32 -> bf16 streaming ----------------
__global__ __launch_bounds__(256) void cvtw_kernel(
    const float* __restrict__ src, ushort* __restrict__ dst, int n8)
{
  const int stride = gridDim.x * 256;
  for (int i = blockIdx.x * 256 + threadIdx.x; i < n8; i += stride) {
    float4 a = ((const float4*)src)[i * 2];
    float4 b = ((const float4*)src)[i * 2 + 1];
    uint4 t;
    t.x = pack2(a.x, a.y); t.y = pack2(a.z, a.w);
    t.z = pack2(b.x, b.y); t.w = pack2(b.z, b.w);
    ((uint4*)dst)[i] = t;
  }
}

// ------- router: logits, top-4, softmax, x->bf16. NO atomics. -------
__global__ __launch_bounds__(256) void router_kernel(
    const float* __restrict__ x, const float* __restrict__ gw,
    ushort* __restrict__ xb, int* __restrict__ topk_id,
    float* __restrict__ topk_w)
{
  const int wid = threadIdx.x >> 6;
  const int lane = threadIdx.x & 63;
  const int t = blockIdx.x * 4 + wid;
  const float4* x4 = (const float4*)(x + (size_t)t * HDIM);
  const float4* gw4 = (const float4*)gw;
  float acc[NEXP];
#pragma unroll
  for (int e = 0; e < NEXP; ++e) acc[e] = 0.f;
#pragma unroll
  for (int i = 0; i < HDIM / 256; ++i) {
    const int idx = i * 64 + lane;
    float4 xv = x4[idx];
    uint2 xp;
    xp.x = pack2(xv.x, xv.y);
    xp.y = pack2(xv.z, xv.w);
    *(uint2*)(xb + (size_t)t * HDIM + idx * 4) = xp;
#pragma unroll
    for (int e = 0; e < NEXP; ++e) {
      float4 wv = gw4[e * (HDIM / 4) + idx];
      acc[e] += xv.x * wv.x + xv.y * wv.y + xv.z * wv.z + xv.w * wv.w;
    }
  }
#pragma unroll
  for (int e = 0; e < NEXP; ++e) {
#pragma unroll
    for (int off = 32; off >= 1; off >>= 1)
      acc[e] += __shfl_xor(acc[e], off);
  }
  if (lane == 0) {
    unsigned taken = 0;
    float vals[KSEL];
    int ids[KSEL];
#pragma unroll
    for (int k = 0; k < KSEL; ++k) {
      float bv = -3.4e38f; int bi = 0;
      for (int e = 0; e < NEXP; ++e)
        if (!((taken >> e) & 1u) && acc[e] > bv) { bv = acc[e]; bi = e; }
      taken |= 1u << bi; vals[k] = bv; ids[k] = bi;
    }
    float m = vals[0], s = 0.f, w[KSEL];
#pragma unroll
    for (int k = 0; k < KSEL; ++k) { w[k] = __expf(vals[k] - m); s += w[k]; }
    float is = 1.f / s;
#pragma unroll
    for (int k = 0; k < KSEL; ++k) {
      topk_id[t * KSEL + k] = ids[k];
      topk_w[t * KSEL + k] = w[k] * is;
    }
  }
}

// --- plan+scatter, single block: LDS histogram/cursors, no global atomics --
__global__ __launch_bounds__(1024) void plan_scatter_kernel(
    const int* __restrict__ topk_id, int* __restrict__ counts,
    int* __restrict__ offsets, int* __restrict__ nWA, int* __restrict__ nWB,
    int* __restrict__ wlA, int* __restrict__ wlB,
    int* __restrict__ rowTok, int* __restrict__ inv)
{
  __shared__ int cnt[NEXP], off[NEXP], cur[NEXP], tiles[NEXP], pre[NEXP];
  const int tid = threadIdx.x;
  if (tid < NEXP) { cnt[tid] = 0; cur[tid] = 0; }
  __syncthreads();
  for (int i = tid; i < TTOK * KSEL; i += 1024)
    atomicAdd(&cnt[topk_id[i]], 1);               // LDS atomics (fast)
  __syncthreads();
  if (tid == 0) {
    int s = 0, p = 0;
    for (int e = 0; e < NEXP; ++e) {
      off[e] = s; s += cnt[e];
      tiles[e] = (cnt[e] + 127) >> 7;
      pre[e] = p; p += tiles[e];
    }
    *nWA = p * NTA;
    *nWB = p * NTB;
  }
  __syncthreads();
  if (tid < NEXP) {
    counts[tid] = cnt[tid];
    offsets[tid] = off[tid];
    const int e = tid, T = tiles[e];
    int idx = pre[e] * NTA;
    for (int nt = 0; nt < NTA; ++nt)
      for (int mt = 0; mt < T; ++mt)
        wlA[idx++] = (e << 12) | (nt << 6) | mt;
  } else if (tid < 2 * NEXP) {
    const int e = tid - NEXP, T = tiles[e];
    int idx = pre[e] * NTB;
    for (int nt = 0; nt < NTB; ++nt)
      for (int mt = 0; mt < T; ++mt)
        wlB[idx++] = (e << 12) | (nt << 6) | mt;
  }
  // scatter: order within an expert is irrelevant (per-row GEMM)
  for (int i = tid; i < TTOK * KSEL; i += 1024) {
    const int e = topk_id[i];
    const int pos = atomicAdd(&cur[e], 1);        // LDS atomic
    const int row = off[e] + pos;
    rowTok[row] = i >> 2;
    inv[i] = row;
  }
}

// ------- gemmA: out[rows][1024] = gathered_x . W^T  (m97 structure) -------
__global__ __launch_bounds__(256) void gemmA_kernel(
    const ushort* __restrict__ xb, const ushort* __restrict__ wb,
    const int* __restrict__ rowTok, const int* __restrict__ counts,
    const int* __restrict__ offsets, const int* __restrict__ nW,
    const int* __restrict__ wl, ushort* __restrict__ outb)
{
  const int nTot = *nW;
  const int L = (blockIdx.x & 7) * (MAXBA / 8) + (blockIdx.x >> 3);
  if (L >= nTot) return;
  const int w = wl[L];
  const int e = w >> 12, nt = (w >> 6) & 63, mt = w & 63;
  const int n_e = counts[e], rowbase = offsets[e];

  __shared__ ushort As[2][128 * 32];
  __shared__ ushort Bs[2][128 * 32];

  const int tid = threadIdx.x;
  const int r0 = tid >> 2;
  const int ck = tid & 3;
  const int sch = (ck ^ ((r0 >> 1) & 3)) << 3;

  const int ar0 = mt * 128 + r0, ar1 = ar0 + 64;
  const int tok0 = rowTok[rowbase + (ar0 < n_e ? ar0 : n_e - 1)];
  const int tok1 = rowTok[rowbase + (ar1 < n_e ? ar1 : n_e - 1)];
  const ushort* pA0 = xb + (size_t)tok0 * HDIM + sch;
  const ushort* pA1 = xb + (size_t)tok1 * HDIM + sch;
  const size_t wbase = (size_t)e * IDIM * HDIM;
  const ushort* pB0 = wb + wbase + (size_t)(nt * 128 + r0) * HDIM + sch;
  const ushort* pB1 = wb + wbase + (size_t)(nt * 128 + r0 + 64) * HDIM + sch;

  const int lane = tid & 63;
  const int wid = tid >> 6;
  const int wr = (wid >> 1) << 6;
  const int wc = (wid & 1) << 6;
  const int lr = lane & 15;
  const int q = lane >> 4;

  f32x4 acc[4][4];
#pragma unroll
  for (int i = 0; i < 4; ++i)
#pragma unroll
    for (int j = 0; j < 4; ++j) acc[i][j] = (f32x4){0.f, 0.f, 0.f, 0.f};

  auto STAGE = [&](int b) {
    gload16(pA0, &As[b][tid * 8]);
    gload16(pA1, &As[b][2048 + tid * 8]);
    gload16(pB0, &Bs[b][tid * 8]);
    gload16(pB1, &Bs[b][2048 + tid * 8]);
    pA0 += 32; pA1 += 32; pB0 += 32; pB1 += 32;
  };

  const int NTK = HDIM / 32;  // 64
  STAGE(0);
  __syncthreads();
  int buf = 0;
  for (int kt = 0; kt < NTK; ++kt) {
    if (kt + 1 < NTK) STAGE(buf ^ 1);
    bf16x8 af[4], bfr[4];
#pragma unroll
    for (int mi = 0; mi < 4; ++mi)
      af[mi] = *(const bf16x8*)&As[buf][swzread(wr + mi * 16 + lr, q)];
#pragma unroll
    for (int ni = 0; ni < 4; ++ni)
      bfr[ni] = *(const bf16x8*)&Bs[buf][swzread(wc + ni * 16 + lr, q)];
#pragma unroll
    for (int mi = 0; mi < 4; ++mi)
#pragma unroll
      for (int ni = 0; ni < 4; ++ni)
        acc[mi][ni] = __builtin_amdgcn_mfma_f32_16x16x32_bf16(af[mi], bfr[ni], acc[mi][ni], 0, 0, 0);
    __syncthreads();
    buf ^= 1;
  }

#pragma unroll
  for (int mi = 0; mi < 4; ++mi) {
#pragma unroll
    for (int ni = 0; ni < 4; ++ni) {
      const int col = nt * 128 + wc + ni * 16 + lr;
#pragma unroll
      for (int r = 0; r < 4; ++r) {
        const int mrow = mt * 128 + wr + mi * 16 + q * 4 + r;
        if (mrow < n_e)
          outb[(size_t)(rowbase + mrow) * IDIM + col] = bf1(acc[mi][ni][r]);
      }
    }
  }
}

// ------- gemmB: po[rows][2048] = hbuf . w2^T  (same structure) -------
__global__ __launch_bounds__(256) void gemmB_kernel(
    const ushort* __restrict__ hb, const ushort* __restrict__ wb,
    const int* __restrict__ counts, const int* __restrict__ offsets,
    const int* __restrict__ nW, const int* __restrict__ wl,
    ushort* __restrict__ po)
{
  const int nTot = *nW;
  const int L = (blockIdx.x & 7) * (MAXBB / 8) + (blockIdx.x >> 3);
  if (L >= nTot) return;
  const int w = wl[L];
  const int e = w >> 12, nt = (w >> 6) & 63, mt = w & 63;
  const int n_e = counts[e], rowbase = offsets[e];

  __shared__ ushort As[2][128 * 32];
  __shared__ ushort Bs[2][128 * 32];

  const int tid = threadIdx.x;
  const int r0 = tid >> 2;
  const int ck = tid & 3;
  const int sch = (ck ^ ((r0 >> 1) & 3)) << 3;

  const int ar0 = mt * 128 + r0, ar1 = ar0 + 64;
  const int g0 = rowbase + (ar0 < n_e ? ar0 : n_e - 1);
  const int g1 = rowbase + (ar1 < n_e ? ar1 : n_e - 1);
  const ushort* pA0 = hb + (size_t)g0 * IDIM + sch;
  const ushort* pA1 = hb + (size_t)g1 * IDIM + sch;
  const size_t wbase = (size_t)e * HDIM * IDIM;
  const ushort* pB0 = wb + wbase + (size_t)(nt * 128 + r0) * IDIM + sch;
  const ushort* pB1 = wb + wbase + (size_t)(nt * 128 + r0 + 64) * IDIM + sch;

  const int lane = tid & 63;
  const int wid = tid >> 6;
  const int wr = (wid >> 1) << 6;
  const int wc = (wid & 1) << 6;
  const int lr = lane & 15;
  const int q = lane >> 4;

  f32x4 acc[4][4];
#pragma unroll
  for (int i = 0; i < 4; ++i)
#pragma unroll
    for (int j = 0; j < 4; ++j) acc[i][j] = (f32x4){0.f, 0.f, 0.f, 0.f};

  auto STAGE = [&](int b) {
    gload16(pA0, &As[b][tid * 8]);
    gload16(pA1, &As[b][2048 + tid * 8]);
    gload16(pB0, &Bs[b][tid * 8]);
    gload16(pB1, &Bs[b][2048 + tid * 8]);
    pA0 += 32; pA1 += 32; pB0 += 32; pB1 += 32;
  };

  const int NTK = IDIM / 32;  // 32
  STAGE(0);
  __syncthreads();
  int buf = 0;
  for (int kt = 0; kt < NTK; ++kt) {
    if (kt + 1 < NTK) STAGE(buf ^ 1);
    bf16x8 af[4], bfr[4];
#pragma unroll
    for (int mi = 0; mi < 4; ++mi)
      af[mi] = *(const bf16x8*)&As[buf][swzread(wr + mi * 16 + lr, q)];
#pragma unroll
    for (int ni = 0; ni < 4; ++ni)
      bfr[ni] = *(const bf16x8*)&Bs[buf][swzread(wc + ni * 16 + lr, q)];
#pragma unroll
    for (int mi = 0; mi < 4; ++mi)
#pragma unroll
      for (int ni = 0; ni < 4; ++ni)
        acc[mi][ni] = __builtin_amdgcn_mfma_f32_16x16x32_bf16(af[mi], bfr[ni], acc[mi][ni], 0, 0, 0);
    __syncthreads();
    buf ^= 1;
  }

#pragma unroll
  for (int mi = 0; mi < 4; ++mi) {
#pragma unroll
    for (int ni = 0; ni < 4; ++ni) {
      const int col = nt * 128 + wc + ni * 16 + lr;
#pragma unroll
      for (int r = 0; r < 4; ++r) {
        const int mrow = mt * 128 + wr + mi * 16 + q * 4 + r;
        if (mrow < n_e)
          po[(size_t)(rowbase + mrow) * HDIM + col] = bf1(acc[mi][ni][r]);
      }
    }
  }
}

// ---------------- silu: h = silu(g) * u, elementwise bf16 ----------------
__global__ __launch_bounds__(256) void silu_kernel(
    const ushort* __restrict__ g, const ushort* __restrict__ u,
    ushort* __restrict__ h, int n8)
{
  const int stride = gridDim.x * 256;
  for (int i = blockIdx.x * 256 + threadIdx.x; i < n8; i += stride) {
    uint4 gv = ((const uint4*)g)[i];
    uint4 uv = ((const uint4*)u)[i];
    uint4 hv;
#pragma unroll
    for (int wd = 0; wd < 4; ++wd) {
      const uint32_t gw2 = (&gv.x)[wd], uw2 = (&uv.x)[wd];
      const float g0 = bf2f((ushort)(gw2 & 0xffff));
      const float g1 = bf2f((ushort)(gw2 >> 16));
      const float u0 = bf2f((ushort)(uw2 & 0xffff));
      const float u1 = bf2f((ushort)(uw2 >> 16));
      const float h0 = (g0 / (1.f + __expf(-g0))) * u0;
      const float h1 = (g1 / (1.f + __expf(-g1))) * u1;
      (&hv.x)[wd] = pack2(h0, h1);
    }
    ((uint4*)h)[i] = hv;
  }
}

// ---------------- combine: out[t] = sum_k w_k * po[row_k] -----------------
__global__ __launch_bounds__(256) void combine_kernel(
    const ushort* __restrict__ po, const int* __restrict__ inv,
    const float* __restrict__ tw, float* __restrict__ out)
{
  const int t = blockIdx.x;
  const int r0 = inv[t * 4 + 0], r1 = inv[t * 4 + 1];
  const int r2 = inv[t * 4 + 2], r3 = inv[t * 4 + 3];
  const float w0 = tw[t * 4 + 0], w1 = tw[t * 4 + 1];
  const float w2v = tw[t * 4 + 2], w3 = tw[t * 4 + 3];
  const int i = threadIdx.x;
  uint4 v0 = *(const uint4*)(po + (size_t)r0 * HDIM + i * 8);
  uint4 v1 = *(const uint4*)(po + (size_t)r1 * HDIM + i * 8);
  uint4 v2 = *(const uint4*)(po + (size_t)r2 * HDIM + i * 8);
  uint4 v3 = *(const uint4*)(po + (size_t)r3 * HDIM + i * 8);
  float o[8];
#pragma unroll
  for (int w = 0; w < 4; ++w) {
    const uint32_t a = (&v0.x)[w], b = (&v1.x)[w], c = (&v2.x)[w], d = (&v3.x)[w];
    o[w * 2 + 0] = w0 * __builtin_bit_cast(float, a << 16) +
                   w1 * __builtin_bit_cast(float, b << 16) +
                   w2v * __builtin_bit_cast(float, c << 16) +
                   w3 * __builtin_bit_cast(float, d << 16);
    o[w * 2 + 1] = w0 * __builtin_bit_cast(float, a & 0xffff0000u) +
                   w1 * __builtin_bit_cast(float, b & 0xffff0000u) +
                   w2v * __builtin_bit_cast(float, c & 0xffff0000u) +
                   w3 * __builtin_bit_cast(float, d & 0xffff0000u);
  }
  float4* o4 = (float4*)(out + (size_t)t * HDIM + i * 8);
  o4[0] = (float4){o[0], o[1], o[2], o[3]};
  o4[1] = (float4){o[4], o[5], o[6], o[7]};
}

extern "C" void kernel_launch(void* const* d_in, const int* in_sizes, int n_in,
                              void* d_out, int out_size, void* d_ws, size_t ws_size,
                              hipStream_t stream) {
  const float* x   = (const float*)d_in[0];
  const float* gw  = (const float*)d_in[1];
  const float* w1g = (const float*)d_in[2];
  const float* w1u = (const float*)d_in[3];
  const float* w2  = (const float*)d_in[4];
  float* out = (float*)d_out;

  char* ws = (char*)d_ws;
  ushort* xb   = (ushort*)(ws + 0);
  ushort* wbuf = (ushort*)(ws + 8388608);
  ushort* gbuf = (ushort*)(ws + 75497472);
  ushort* ubuf = (ushort*)(ws + 92274688);
  ushort* hbuf = (ushort*)(ws + 109051904);
  ushort* po   = (ushort*)(ws + 125829120);
  int*    tkid   = (int*)(ws + 159383552);
  float*  tkw    = (float*)(ws + 159383552 + 32768);
  int*    rowTok = (int*)(ws + 159383552 + 65536);
  int*    inv    = (int*)(ws + 159383552 + 98304);
  int*    ctrl   = (int*)(ws + 159514624);
  int* counts  = ctrl;           // 16
  int* offsets = ctrl + 32;      // 17
  int* nWA     = ctrl + 50;      // 1
  int* nWB     = ctrl + 51;      // 1
  int* wlA     = ctrl + 64;      // MAXBA (640)
  int* wlB     = ctrl + 64 + MAXBA;  // MAXBB (1280)

  const int NW8 = (NEXP * IDIM * HDIM) / 8;  // per weight tensor

  router_kernel<<<TTOK / 4, 256, 0, stream>>>(x, gw, xb, tkid, tkw);
  plan_scatter_kernel<<<1, 1024, 0, stream>>>(tkid, counts, offsets, nWA, nWB,
                                              wlA, wlB, rowTok, inv);
  // gate pass
  cvtw_kernel<<<2048, 256, 0, stream>>>(w1g, wbuf, NW8);
  gemmA_kernel<<<MAXBA, 256, 0, stream>>>(xb, wbuf, rowTok, counts, offsets,
                                          nWA, wlA, gbuf);
  // up pass (wbuf reused; stream order serializes)
  cvtw_kernel<<<2048, 256, 0, stream>>>(w1u, wbuf, NW8);
  gemmA_kernel<<<MAXBA, 256, 0, stream>>>(xb, wbuf, rowTok, counts, offsets,
                                          nWA, wlA, ubuf);
  // h = silu(g) * u
  silu_kernel<<<2048, 256, 0, stream>>>(gbuf, ubuf, hbuf, (TTOK * KSEL * IDIM) / 8);
  // down pass
  cvtw_kernel<<<2048, 256, 0, stream>>>(w2, wbuf, NW8);
  gemmB_kernel<<<MAXBB, 256, 0, stream>>>(hbuf, wbuf, counts, offsets,
                                          nWB, wlB, po);
  combine_kernel<<<TTOK, 256, 0, stream>>>(po, inv, tkw, out);
}